// Round 6
// baseline (148.536 us; speedup 1.0000x reference)
//
#include <hip/hip_runtime.h>
#include <hip/hip_bf16.h>
#include <math.h>

// MultiHeadAttention: B=2, S=2048, E=1024, H=16, D=64, fp32 in/out.
// Round 6:
//  - prep_f16: ONE kernel for x->f16 and all 4 W transposes (was 5 launches).
//  - gemm_f16<0>: fused QKV; V-tiles computed with SWAPPED mfma operands so
//    the V^T epilogue stores are 32B-contiguous (was 2B scatter).
//  - attn_f16v3: double-buffered K/V staging (T3-minimal: issue next tile's
//    global_load_lds right after the barrier, compute overlaps the loads),
//    one barrier per 128-key tile, s_setprio(1) around MFMA clusters (T5).
//  - gemm_f16<1>: out = Of @ Wo^T + bo.

#define S_LEN 2048
#define EMB   1024
#define HN    16
#define HD    64
#define BATCH 2
#define MROWS (BATCH * S_LEN)        // 4096
#define NEL   ((size_t)MROWS * EMB)  // 4,194,304

typedef _Float16 f16x8 __attribute__((ext_vector_type(8)));
typedef _Float16 f16x4 __attribute__((ext_vector_type(4)));
typedef float    f32x4  __attribute__((ext_vector_type(4)));
typedef float    f32x16 __attribute__((ext_vector_type(16)));
typedef unsigned u32x4  __attribute__((ext_vector_type(4)));

#define GLOAD_LDS16(g, l) \
  __builtin_amdgcn_global_load_lds((const __attribute__((address_space(1))) void*)(g), \
                                   (__attribute__((address_space(3))) void*)(l), 16, 0, 0)

__device__ __forceinline__ float exp2fast(float x) {
#if __has_builtin(__builtin_amdgcn_exp2f)
  return __builtin_amdgcn_exp2f(x);
#else
  return __expf(x * 0.69314718056f);
#endif
}

__device__ __forceinline__ unsigned pk_f16(float a, float b) {
#if __has_builtin(__builtin_amdgcn_cvt_pkrtz)
  auto h = __builtin_amdgcn_cvt_pkrtz(a, b);
  return __builtin_bit_cast(unsigned, h);
#else
  unsigned lo = (unsigned)__builtin_bit_cast(unsigned short, (_Float16)a);
  unsigned hi = (unsigned)__builtin_bit_cast(unsigned short, (_Float16)b);
  return lo | (hi << 16);
#endif
}

__device__ __forceinline__ f32x16 mfma32(f16x8 a, f16x8 b, f32x16 c) {
  return __builtin_amdgcn_mfma_f32_32x32x16_f16(a, b, c, 0, 0, 0);
}
__device__ __forceinline__ f32x4 mfma16(f16x8 a, f16x8 b, f32x4 c) {
  return __builtin_amdgcn_mfma_f32_16x16x32_f16(a, b, c, 0, 0, 0);
}

// ---------------------------------------------------------------------------
// fused prep: blocks [0,2048): x -> xf (fp16). blocks [2048,3072): W
// transposes, job j = (bid-2048)>>8 in {Wq,Wk,Wv,Wo} -> (N,K) fp16.
// ---------------------------------------------------------------------------
__global__ __launch_bounds__(256)
void prep_f16(const float* __restrict__ x,
              const float* __restrict__ Wq, const float* __restrict__ Wk,
              const float* __restrict__ Wv, const float* __restrict__ Wo,
              _Float16* __restrict__ xf, _Float16* __restrict__ Wt,
              _Float16* __restrict__ Wot) {
  __shared__ float tile[64][65];
  const int bid = blockIdx.x;
  const int tt  = threadIdx.x;
  if (bid < 2048) {
    const int i = bid * 256 + tt;        // exactly NEL/8 iterations
    const float4* s = (const float4*)x + (size_t)i * 2;
    float4 a = s[0], b = s[1];
    f16x8 o = {(_Float16)a.x, (_Float16)a.y, (_Float16)a.z, (_Float16)a.w,
               (_Float16)b.x, (_Float16)b.y, (_Float16)b.z, (_Float16)b.w};
    *((f16x8*)xf + i) = o;
    return;
  }
  const int j   = bid - 2048;
  const int job = j >> 8;                // 0..3
  const int tl  = j & 255;
  const int bn  = (tl & 15) * 64, bk = (tl >> 4) * 64;
  const float* W = (job == 0) ? Wq : (job == 1) ? Wk : (job == 2) ? Wv : Wo;
  _Float16* dst = (job == 3) ? Wot : Wt + (size_t)job * EMB * EMB;
  const int c = tt & 63, r4 = tt >> 6;
#pragma unroll
  for (int jj = 0; jj < 16; ++jj) {
    int r = r4 * 16 + jj;
    tile[r][c] = W[(size_t)(bk + r) * EMB + bn + c];
  }
  __syncthreads();
#pragma unroll
  for (int jj = 0; jj < 16; ++jj) {
    int rr = r4 * 16 + jj;
    dst[(size_t)(bn + rr) * EMB + bk + c] = (_Float16)tile[c][rr];
  }
}

// ---------------------------------------------------------------------------
// fp16 MFMA GEMM. A:(4096,1024) fp16 row-major, Bt:(Ncols,1024) fp16.
// MODE 0: Ncols=3072 -> Qf(*0.125*log2e), Kf (b,h,s,d); V-tiles use swapped
//         mfma operands -> acc holds the transposed tile -> VfT (b,h,d,s)
//         written as 32B-contiguous runs.
// MODE 1: Ncols=1024 -> fp32 (M,N) + bias.
// ---------------------------------------------------------------------------
template<bool SW>
__device__ __forceinline__ void gemm_kloop(
    const _Float16* __restrict__ gA, const _Float16* __restrict__ gB,
    _Float16* As, _Float16* Bs,
    const _Float16* ldsA0, const _Float16* ldsB0,
    int wr, int wc, int ln, int kg, f32x4 (&acc)[4][4]) {
#pragma unroll 1
  for (int k0 = 0; k0 < EMB; k0 += 32) {
    __syncthreads();
    GLOAD_LDS16(gA + k0,            (void*)ldsA0);
    GLOAD_LDS16(gA + k0 + 16 * EMB, (void*)(ldsA0 + 512));
    GLOAD_LDS16(gB + k0,            (void*)ldsB0);
    GLOAD_LDS16(gB + k0 + 16 * EMB, (void*)(ldsB0 + 512));
    __syncthreads();
    f16x8 a[4], b[4];
#pragma unroll
    for (int mi = 0; mi < 4; ++mi)
      a[mi] = *(const f16x8*)&As[(wr * 64 + mi * 16 + ln) * 32 + kg * 8];
#pragma unroll
    for (int ni = 0; ni < 4; ++ni)
      b[ni] = *(const f16x8*)&Bs[(wc * 64 + ni * 16 + ln) * 32 + kg * 8];
#pragma unroll
    for (int mi = 0; mi < 4; ++mi)
#pragma unroll
      for (int ni = 0; ni < 4; ++ni)
        acc[mi][ni] = SW ? mfma16(b[ni], a[mi], acc[mi][ni])
                         : mfma16(a[mi], b[ni], acc[mi][ni]);
  }
}

template<int MODE>
__global__ __launch_bounds__(256)
void gemm_f16(const _Float16* __restrict__ A, const _Float16* __restrict__ Bt,
              int Ncols,
              _Float16* __restrict__ qf, _Float16* __restrict__ kf,
              _Float16* __restrict__ vf, float* __restrict__ outF,
              const float* __restrict__ b0, const float* __restrict__ b1,
              const float* __restrict__ b2) {
  __shared__ _Float16 As[128 * 32];
  __shared__ _Float16 Bs[128 * 32];
  const int tid  = threadIdx.x;
  const int lane = tid & 63, w = tid >> 6;
  const int ln = lane & 15, kg = lane >> 4;
  const int wr = w >> 1, wc = w & 1;

  int wg = blockIdx.x;
  { int q = gridDim.x >> 3; wg = (wg & 7) * q + (wg >> 3); }
  const int nbx  = Ncols >> 7;
  const int row0 = (wg / nbx) << 7;
  const int col0 = (wg % nbx) << 7;

  const int cA0 = w * 128 + lane;
  const int arow0 = cA0 >> 2, acol0 = (cA0 & 3) * 8;

  f32x4 acc[4][4];
#pragma unroll
  for (int mi = 0; mi < 4; ++mi)
#pragma unroll
    for (int ni = 0; ni < 4; ++ni) acc[mi][ni] = (f32x4){0.f, 0.f, 0.f, 0.f};

  const _Float16* ldsA0 = As + (size_t)(w * 2) * 512;
  const _Float16* ldsB0 = Bs + (size_t)(w * 2) * 512;
  const _Float16* gA = A  + (size_t)(row0 + arow0) * EMB + acol0;
  const _Float16* gB = Bt + (size_t)(col0 + arow0) * EMB + acol0;

  const bool is_v = (MODE == 0) && (col0 >= 2048);
  if (is_v) gemm_kloop<true >(gA, gB, As, Bs, ldsA0, ldsB0, wr, wc, ln, kg, acc);
  else      gemm_kloop<false>(gA, gB, As, Bs, ldsA0, ldsB0, wr, wc, ln, kg, acc);

  if (MODE == 1) {
#pragma unroll
    for (int mi = 0; mi < 4; ++mi)
#pragma unroll
      for (int ni = 0; ni < 4; ++ni) {
        const int n = col0 + wc * 64 + ni * 16 + ln;
        const float bias = b0[n];
#pragma unroll
        for (int r = 0; r < 4; ++r) {
          const int m = row0 + wr * 64 + mi * 16 + kg * 4 + r;
          outF[(size_t)m * EMB + n] = acc[mi][ni][r] + bias;
        }
      }
  } else if (!is_v) {
    // Q or K tile: C layout col=ln (n dim), reg = m dim
#pragma unroll
    for (int mi = 0; mi < 4; ++mi)
#pragma unroll
      for (int ni = 0; ni < 4; ++ni) {
        const int n = col0 + wc * 64 + ni * 16 + ln;
        const int mat = n >> 10, e = n & 1023;
        const float bias = (mat == 0 ? b0 : b1)[e];
        const int h = e >> 6, d = e & 63;
#pragma unroll
        for (int r = 0; r < 4; ++r) {
          const int m = row0 + wr * 64 + mi * 16 + kg * 4 + r;
          const int bb = m >> 11, ss = m & 2047;
          const int bh = bb * HN + h;
          float val = acc[mi][ni][r] + bias;
          if (mat == 0) {
            // Q pre-scaled by (1/sqrt(D)) * log2(e) for exp2-domain softmax
            qf[((size_t)bh * S_LEN + ss) * HD + d] = (_Float16)(val * 0.18033688f);
          } else {
            kf[((size_t)bh * S_LEN + ss) * HD + d] = (_Float16)val;
          }
        }
      }
  } else {
    // V tile, swapped: C layout col=ln = m (s dim), reg = n (d dim)
#pragma unroll
    for (int mi = 0; mi < 4; ++mi)
#pragma unroll
      for (int ni = 0; ni < 4; ++ni) {
#pragma unroll
        for (int r = 0; r < 4; ++r) {
          const int n = col0 + wc * 64 + ni * 16 + kg * 4 + r;
          const int e = n - 2048;
          const int h = e >> 6, d = e & 63;
          const int m = row0 + wr * 64 + mi * 16 + ln;
          const int bb = m >> 11, ss = m & 2047;
          const int bh = bb * HN + h;
          float val = acc[mi][ni][r] + b2[e];
          vf[((size_t)bh * HD + d) * S_LEN + ss] = (_Float16)val;
        }
      }
  }
}

// ---------------------------------------------------------------------------
// Swapped-operand 32x32 flash attention, double-buffered staging.
// Block = 4 waves x 32 q = 128 q. KVBLK = 128 keys/tile, ONE barrier/tile:
//   prologue STAGE(buf0); loop { sync; STAGE(buf^1, t+1); compute(buf); }
// mfma_f32_32x32x16_f16: A row=lane&31,k=(lane>>5)*8+j; B col=lane&31;
// C/D col=lane&31, row=(r&3)+8*(r>>2)+4*(lane>>5).
// QK^T = mfma(K,Q) -> S^T, q=lane&31 (lane-local softmax + 1 shfl);
// PV = mfma(V,P) -> O^T; P rebuilt in-register (cvt_pkrtz + shfl_xor(32)).
// ---------------------------------------------------------------------------
__global__ __launch_bounds__(256)
void attn_f16v3(const _Float16* __restrict__ Qf, const _Float16* __restrict__ Kf,
                const _Float16* __restrict__ VfT, _Float16* __restrict__ Of) {
  __shared__ _Float16 KS[2][2][4096];  // [buf][key-half][64 rows x 64 d]
  __shared__ _Float16 VS[2][2][4096];  // [buf][key-half][64 d x 64 key]

  const int tid  = threadIdx.x;
  const int lane = tid & 63, w = tid >> 6;
  const int ql = lane & 31;
  const int hi = lane >> 5;

  // XCD-chunked mapping: XCD x owns bh in [4x,4x+4) -> K+V (2MB) fits L2.
  const int logical = ((blockIdx.x & 7) << 6) | (blockIdx.x >> 3);
  const int bh = logical >> 4;
  const int qc = logical & 15;
  const int q0w = (qc << 7) + (w << 5);

  const size_t qbase = ((size_t)bh * S_LEN + q0w + ql) * HD + hi * 8;
  f16x8 qa[4];
#pragma unroll
  for (int ds = 0; ds < 4; ++ds) qa[ds] = *(const f16x8*)&Qf[qbase + ds * 16];

  f32x16 o0 = {}, o1 = {};
  float m = -INFINITY, lsum = 0.f;

  // staging: chunk c (row=c>>3, pos=c&7) holds global 16B-slot ((c&7)^(row&7))
  const int cA = tid, cB = tid + 256;
  const int rA = cA >> 3, sA = ((cA & 7) ^ (rA & 7)) * 8;
  const int rB = cB >> 3, sB = ((cB & 7) ^ (rB & 7)) * 8;
  const _Float16* KB = Kf  + (size_t)bh * S_LEN * HD;
  const _Float16* VB = VfT + (size_t)bh * HD * S_LEN;

#define STAGE(buf, k0) do { \
    GLOAD_LDS16(KB + (size_t)((k0) + rA) * HD + sA,       &KS[buf][0][cA * 8]); \
    GLOAD_LDS16(KB + (size_t)((k0) + rB) * HD + sB,       &KS[buf][0][cB * 8]); \
    GLOAD_LDS16(KB + (size_t)((k0) + 64 + rA) * HD + sA,  &KS[buf][1][cA * 8]); \
    GLOAD_LDS16(KB + (size_t)((k0) + 64 + rB) * HD + sB,  &KS[buf][1][cB * 8]); \
    GLOAD_LDS16(VB + (size_t)rA * S_LEN + (k0) + sA,      &VS[buf][0][cA * 8]); \
    GLOAD_LDS16(VB + (size_t)rB * S_LEN + (k0) + sB,      &VS[buf][0][cB * 8]); \
    GLOAD_LDS16(VB + (size_t)rA * S_LEN + (k0) + 64 + sA, &VS[buf][1][cA * 8]); \
    GLOAD_LDS16(VB + (size_t)rB * S_LEN + (k0) + 64 + sB, &VS[buf][1][cB * 8]); \
  } while (0)

  STAGE(0, 0);
  int cur = 0;
#pragma unroll 1
  for (int t = 0; t < S_LEN / 128; ++t) {
    __syncthreads();  // drains vmcnt: tile t ready in buf cur; buf cur^1 free
    if (t + 1 < S_LEN / 128) STAGE(cur ^ 1, (t + 1) * 128);  // overlap w/ compute

#pragma unroll
    for (int kh = 0; kh < 2; ++kh) {
      // ---- QK^T ----
      f32x16 sf0 = {}, sf1 = {};
      __builtin_amdgcn_s_setprio(1);
#pragma unroll
      for (int ds = 0; ds < 4; ++ds) {
        const int sl = ((ds * 2 + hi) ^ (ql & 7)) * 8;
        f16x8 ka0 = *(const f16x8*)&KS[cur][kh][ql * 64 + sl];
        f16x8 ka1 = *(const f16x8*)&KS[cur][kh][(32 + ql) * 64 + sl];
        sf0 = mfma32(ka0, qa[ds], sf0);
        sf1 = mfma32(ka1, qa[ds], sf1);
      }
      __builtin_amdgcn_s_setprio(0);

      // ---- row max (lane-local tree + one cross-half shfl) ----
      float mx[8];
#pragma unroll
      for (int i = 0; i < 8; ++i)
        mx[i] = fmaxf(fmaxf(sf0[2 * i], sf0[2 * i + 1]),
                      fmaxf(sf1[2 * i], sf1[2 * i + 1]));
      float pm = fmaxf(fmaxf(fmaxf(mx[0], mx[1]), fmaxf(mx[2], mx[3])),
                       fmaxf(fmaxf(mx[4], mx[5]), fmaxf(mx[6], mx[7])));
      pm = fmaxf(pm, __shfl_xor(pm, 32));

      // ---- defer-max rescale (THR=8 in log2 domain) ----
      if (!__all(pm <= m + 8.f)) {
        float mn  = fmaxf(m, pm);
        float scl = exp2fast(m - mn);  // first tile: exp2(-inf)=0
        m = mn;
        lsum *= scl;
#pragma unroll
        for (int i = 0; i < 16; ++i) { o0[i] *= scl; o1[i] *= scl; }
      }

      // ---- p = exp2(s-m); pack f16 pairs; accumulate l ----
      unsigned wv[16];
#pragma unroll
      for (int i = 0; i < 8; ++i) {
        float p0 = exp2fast(sf0[2 * i] - m), p1 = exp2fast(sf0[2 * i + 1] - m);
        float p2 = exp2fast(sf1[2 * i] - m), p3 = exp2fast(sf1[2 * i + 1] - m);
        lsum += (p0 + p1) + (p2 + p3);
        wv[i]     = pk_f16(p0, p1);
        wv[8 + i] = pk_f16(p2, p3);
      }

      // ---- PV: rebuild B-frags in-register, accumulate O^T ----
      __builtin_amdgcn_s_setprio(1);
#pragma unroll
      for (int ks = 0; ks < 4; ++ks) {
        const int base = (ks >> 1) * 8 + (ks & 1) * 4;
        unsigned a0 = wv[base + 0], a1 = wv[base + 1];
        unsigned a2 = wv[base + 2], a3 = wv[base + 3];
        unsigned own0 = hi ? a2 : a0, own1 = hi ? a3 : a1;
        unsigned ps0  = hi ? a0 : a2, ps1  = hi ? a1 : a3;
        unsigned rc0 = __shfl_xor(ps0, 32), rc1 = __shfl_xor(ps1, 32);
        u32x4 pw;
        pw[0] = hi ? rc0 : own0;  pw[1] = hi ? rc1 : own1;
        pw[2] = hi ? own0 : rc0;  pw[3] = hi ? own1 : rc1;
        f16x8 pb = __builtin_bit_cast(f16x8, pw);

        const int sl = ((ks * 2 + hi) ^ (ql & 7)) * 8;
        f16x8 va0 = *(const f16x8*)&VS[cur][kh][ql * 64 + sl];
        f16x8 va1 = *(const f16x8*)&VS[cur][kh][(32 + ql) * 64 + sl];
        o0 = mfma32(va0, pb, o0);
        o1 = mfma32(va1, pb, o1);
      }
      __builtin_amdgcn_s_setprio(0);
    }
    cur ^= 1;
  }
#undef STAGE

  // ---- epilogue ----
  float lt  = lsum + __shfl_xor(lsum, 32);
  float inv = 1.0f / lt;
  const int b = bh >> 4, h = bh & 15;
  _Float16* ob = Of + ((size_t)(b * S_LEN + q0w + ql)) * EMB + (h << 6);
#pragma unroll
  for (int t = 0; t < 4; ++t) {
    f16x4 v0, v1;
#pragma unroll
    for (int j = 0; j < 4; ++j) {
      v0[j] = (_Float16)(o0[4 * t + j] * inv);
      v1[j] = (_Float16)(o1[4 * t + j] * inv);
    }
    *(f16x4*)&ob[8 * t + 4 * hi]      = v0;
    *(f16x4*)&ob[32 + 8 * t + 4 * hi] = v1;
  }
}

// ---------------------------------------------------------------------------

extern "C" void kernel_launch(void* const* d_in, const int* in_sizes, int n_in,
                              void* d_out, int out_size, void* d_ws, size_t ws_size,
                              hipStream_t stream) {
  const float* x  = (const float*)d_in[0];
  const float* Wq = (const float*)d_in[2];
  const float* bq = (const float*)d_in[3];
  const float* Wk = (const float*)d_in[4];
  const float* bk = (const float*)d_in[5];
  const float* Wv = (const float*)d_in[6];
  const float* bv = (const float*)d_in[7];
  const float* Wo = (const float*)d_in[8];
  const float* bo = (const float*)d_in[9];
  float* out = (float*)d_out;

  // workspace: 40 MiB of fp16 tensors
  _Float16* Qf  = (_Float16*)d_ws;
  _Float16* Kf  = Qf + NEL;
  _Float16* VfT = Kf + NEL;              // (b,h,d,s)
  _Float16* xf  = VfT + NEL;
  _Float16* Of  = xf;                    // alias: x consumed before attn writes
  _Float16* Wt  = xf + NEL;              // (3072,1024)
  _Float16* Wot = Wt + 3 * (size_t)EMB * EMB;

  // fused prep: x cvt (2048 blocks) + 4 W transposes (1024 blocks)
  prep_f16<<<dim3(3072), 256, 0, stream>>>(x, Wq, Wk, Wv, Wo, xf, Wt, Wot);

  // fused QKV projection -> Qf(*0.125*log2e), Kf (b,h,s,d), VfT (b,h,d,s)
  gemm_f16<0><<<dim3((MROWS / 128) * (3072 / 128)), 256, 0, stream>>>(
      xf, Wt, 3072, Qf, Kf, VfT, nullptr, bq, bk, bv);

  // flash attention -> Of (b,s,E) fp16
  attn_f16v3<<<dim3(BATCH * HN * (S_LEN / 128)), 256, 0, stream>>>(Qf, Kf, VfT, Of);

  // output projection -> fp32 out
  gemm_f16<1><<<dim3((MROWS / 128) * (EMB / 128)), 256, 0, stream>>>(
      Of, Wot, 1024, nullptr, nullptr, nullptr, out, bo, nullptr, nullptr);
}